// Round 6
// baseline (1144.083 us; speedup 1.0000x reference)
//
#include <hip/hip_runtime.h>

#define E_TOTAL 500000
#define N_NODES 50000
#define DN 128
#define CIN 384      // 2*DN + D_EDGE
#define DH 512
#define DOUT 128
#define MT 64        // edges per tile
#define NTILE 7813   // ceil(E/MT)
#define NPERS 256    // persistent blocks, 1 per CU
#define SEG_B 16384  // sA seg: 64 rows x 256B
#define ABUF_B 49152 // 3 segs per sA buffer
#define SH_OFF 98304 // sH base: 64 rows x 1024B (after 2 sA buffers)
#define SO_LD 132    // sO leading dim (f32)

typedef short short8 __attribute__((ext_vector_type(8)));
typedef float f32x4 __attribute__((ext_vector_type(4)));

__device__ inline short f2bf(float f) {
    unsigned int u = __float_as_uint(f);
    u = (u + 0x7FFFu + ((u >> 16) & 1u)) >> 16;
    return (short)u;
}

__device__ inline void gload16(const void* gsrc, void* ldst) {
    __builtin_amdgcn_global_load_lds(
        (const __attribute__((address_space(1))) unsigned int*)gsrc,
        (__attribute__((address_space(3))) unsigned int*)ldst, 16, 0, 0);
}

__device__ inline short4 cvt4(float4 v) {
    short4 p;
    p.x = f2bf(v.x); p.y = f2bf(v.y); p.z = f2bf(v.z); p.w = f2bf(v.w);
    return p;
}

// Fused prep: blocks 0..255 transpose W1/W2 -> bf16; blocks 256+ convert x -> bf16.
__global__ void prep_all(const float* __restrict__ w1,
                         const float* __restrict__ w2,
                         const float* __restrict__ x,
                         short* __restrict__ w1t,
                         short* __restrict__ w2t,
                         short* __restrict__ xb) {
    __shared__ float t[32][33];
    int b = blockIdx.x;
    if (b >= 256) {
        int i = (b - 256) * 256 + threadIdx.x;      // < 800000 exact
        const float4* s = reinterpret_cast<const float4*>(x) + (size_t)i * 2;
        float4 a = s[0], c = s[1];
        short8 p;
        p[0] = f2bf(a.x); p[1] = f2bf(a.y); p[2] = f2bf(a.z); p[3] = f2bf(a.w);
        p[4] = f2bf(c.x); p[5] = f2bf(c.y); p[6] = f2bf(c.z); p[7] = f2bf(c.w);
        reinterpret_cast<short8*>(xb)[i] = p;
        return;
    }
    const float* src; short* dst; int R, C, tr, tc;
    if (b < 192) { src = w1; dst = w1t; R = 384; C = 512; tr = b >> 4; tc = b & 15; }
    else { b -= 192; src = w2; dst = w2t; R = 512; C = 128; tr = b >> 2; tc = b & 3; }
    int lx = threadIdx.x & 31, ly = threadIdx.x >> 5;   // 32 x 8
#pragma unroll
    for (int p = 0; p < 4; p++) {
        int r = tr * 32 + p * 8 + ly;
        t[p * 8 + ly][lx] = src[(size_t)r * C + tc * 32 + lx];
    }
    __syncthreads();
#pragma unroll
    for (int p = 0; p < 4; p++) {
        int c = tc * 32 + p * 8 + ly;                   // dst row = src col
        dst[(size_t)c * R + tr * 32 + lx] = f2bf(t[lx][p * 8 + ly]);
    }
}

// Persistent pipelined edge MLP. MT=64, 1024 thr (16 waves), 1 block/CU.
// LDS 160KB exact: sA0(48K) | sA1(48K) | sH(64K, sO f32 aliases).
// Per tile: issue next-tile gathers (gload_lds, zero regs; ea f32 -> 8 regs
// write-late) BEFORE GEMM1 so HBM latency hides under compute; 4 barriers.
// GEMM1: wave w owns N cols w*32..+31 over all 64 M rows (acc 32 regs).
// GEMM2: wave (half=w>>3, wn=w&7): rows half*32+.., cols wn*16+...
template<bool XB>
__global__ __launch_bounds__(1024, 4) void edge_mlp(
        const short* __restrict__ xb,     // bf16 [N_NODES][128] (XB=1)
        const float* __restrict__ xf,     // f32 fallback (XB=0)
        const int* __restrict__ ei,       // [2][E]
        const float* __restrict__ ea,
        const float* __restrict__ b1,
        const float* __restrict__ b2,
        const short* __restrict__ w1t,    // bf16 [512][384]
        const short* __restrict__ w2t,    // bf16 [128][512]
        float* __restrict__ out) {
    __shared__ short sBuf[81920];         // 160 KB
    char* sb = (char*)sBuf;

    const int tid = threadIdx.x;
    const int wave = tid >> 6;            // 0..15
    const int lane = tid & 63;
    const int l16 = lane & 15;
    const int quad = lane >> 4;
    const int xorv = (l16 & 7) << 4;      // GEMM-read row-XOR (row%16 == l16)

    // persistent loop invariants
    const short* base1 = w1t + (size_t)(wave * 32 + l16) * CIN + quad * 8;
    const int wn = wave & 7, half = wave >> 3;
    const short* base2 = w2t + (size_t)(wn * 16 + l16) * DH + quad * 8;
    float4 b1v[2];
#pragma unroll
    for (int nt = 0; nt < 2; nt++)
        b1v[nt] = *reinterpret_cast<const float4*>(&b1[wave * 32 + nt * 16 + quad * 4]);
    float4 b2v = *reinterpret_cast<const float4*>(&b2[wn * 16 + quad * 4]);

    const int grow = wave * 4 + (lane >> 4);   // this lane's gather row (0..63)
    const int grx = (grow & 7) << 4;           // gather-row swizzle

    int t = blockIdx.x;
    int cur = 0;

    // ---- prologue: gather tile t -> buf0 ----
    {
        int e = t * MT + grow; e = e < E_TOTAL ? e : E_TOTAL - 1;
        if (XB) {
#pragma unroll
            for (int s = 0; s < 2; s++) {
                int idx = ei[s * E_TOTAL + e];
                int lc = (l16 * 16) ^ grx;
                gload16((const char*)(xb + (size_t)idx * DN) + lc,
                        sb + s * SEG_B + wave * 1024);
            }
        } else {
#pragma unroll
            for (int s = 0; s < 2; s++) {
                int idx = ei[s * E_TOTAL + e];
                const float4* xp = reinterpret_cast<const float4*>(xf + (size_t)idx * DN);
                float4 fa = xp[l16], fb = xp[l16 + 16];
                char* seg = sb + s * SEG_B + grow * 256;
                *reinterpret_cast<short4*>(seg + ((l16 * 8) ^ grx)) = cvt4(fa);
                *reinterpret_cast<short4*>(seg + ((l16 * 8 + 128) ^ grx)) = cvt4(fb);
            }
        }
        const float4* ep = reinterpret_cast<const float4*>(ea + (size_t)e * DN);
        float4 fa = ep[l16], fb = ep[l16 + 16];
        char* seg2 = sb + 2 * SEG_B + grow * 256;
        *reinterpret_cast<short4*>(seg2 + ((l16 * 8) ^ grx)) = cvt4(fa);
        *reinterpret_cast<short4*>(seg2 + ((l16 * 8 + 128) ^ grx)) = cvt4(fb);
        __syncthreads();                  // gathers landed (vmcnt+lgkm drain)
    }

#pragma unroll 1
    for (;;) {
        const int tn = t + NPERS;
        const bool hasN = tn < NTILE;
        const int nxt = cur ^ 1;
        char* curA = sb + cur * ABUF_B;
        char* nxtA = sb + nxt * ABUF_B;

        // ---- 1) issue next-tile gathers (land by B1; hidden under GEMM1) ----
        float4 efa, efb;                  // ea staged (write-late)
        float4 xga[2], xgb[2];            // XB=0 staged
        if (hasN) {
            int e = tn * MT + grow; e = e < E_TOTAL ? e : E_TOTAL - 1;
            if (XB) {
#pragma unroll
                for (int s = 0; s < 2; s++) {
                    int idx = ei[s * E_TOTAL + e];
                    int lc = (l16 * 16) ^ grx;
                    gload16((const char*)(xb + (size_t)idx * DN) + lc,
                            nxtA + s * SEG_B + wave * 1024);
                }
            } else {
#pragma unroll
                for (int s = 0; s < 2; s++) {
                    int idx = ei[s * E_TOTAL + e];
                    const float4* xp = reinterpret_cast<const float4*>(xf + (size_t)idx * DN);
                    xga[s] = xp[l16]; xgb[s] = xp[l16 + 16];
                }
            }
            const float4* ep = reinterpret_cast<const float4*>(ea + (size_t)e * DN);
            efa = ep[l16]; efb = ep[l16 + 16];
        }

        // ---- 2) GEMM1: acc[nt][mt] = h^T frags (reads curA only) ----
        f32x4 acc[2][4] = {};
        {
            short8 bb[2];
            bb[0] = *reinterpret_cast<const short8*>(base1);
            bb[1] = *reinterpret_cast<const short8*>(base1 + 16 * CIN);
            for (int k = 0; k < CIN; k += 32) {
                short8 bn[2];
                if (k + 32 < CIN) {
                    bn[0] = *reinterpret_cast<const short8*>(base1 + k + 32);
                    bn[1] = *reinterpret_cast<const short8*>(base1 + 16 * CIN + k + 32);
                }
                const char* abase = curA + (k >> 7) * SEG_B;
                const int ko = 2 * (k & 127);
                short8 a[4];
#pragma unroll
                for (int mt = 0; mt < 4; mt++) {
                    int m = mt * 16 + l16;
                    a[mt] = *reinterpret_cast<const short8*>(
                        abase + m * 256 + ((ko + quad * 16) ^ xorv));
                }
#pragma unroll
                for (int nt = 0; nt < 2; nt++)
#pragma unroll
                    for (int mt = 0; mt < 4; mt++)
                        acc[nt][mt] = __builtin_amdgcn_mfma_f32_16x16x32_bf16(bb[nt], a[mt], acc[nt][mt], 0, 0, 0);
                if (k + 32 < CIN) { bb[0] = bn[0]; bb[1] = bn[1]; }
            }
        }

        // ---- 3) epilogue: +b1, relu, bf16 -> sH (disjoint from sA: no barrier) ----
#pragma unroll
        for (int nt = 0; nt < 2; nt++) {
#pragma unroll
            for (int mt = 0; mt < 4; mt++) {
                int m = mt * 16 + l16;
                float4 v;
                v.x = fmaxf(acc[nt][mt][0] + b1v[nt].x, 0.0f);
                v.y = fmaxf(acc[nt][mt][1] + b1v[nt].y, 0.0f);
                v.z = fmaxf(acc[nt][mt][2] + b1v[nt].z, 0.0f);
                v.w = fmaxf(acc[nt][mt][3] + b1v[nt].w, 0.0f);
                *reinterpret_cast<short4*>(
                    sb + SH_OFF + m * 1024 + ((wave * 64 + nt * 32 + quad * 8) ^ xorv)) = cvt4(v);
            }
        }
        __syncthreads();                  // B1: sH visible; next-tile gloads drained

        // ---- 4) GEMM2: out^T frags ----
        f32x4 acc2[2] = {};
        {
            short8 bw = *reinterpret_cast<const short8*>(base2);
#pragma unroll
            for (int kk = 0; kk < 16; kk++) {
                short8 bnx = bw;
                if (kk < 15) bnx = *reinterpret_cast<const short8*>(base2 + (kk + 1) * 32);
                short8 hf[2];
#pragma unroll
                for (int mt = 0; mt < 2; mt++) {
                    int m = half * 32 + mt * 16 + l16;
                    hf[mt] = *reinterpret_cast<const short8*>(
                        sb + SH_OFF + m * 1024 + ((kk * 64 + quad * 16) ^ xorv));
                }
#pragma unroll
                for (int mt = 0; mt < 2; mt++)
                    acc2[mt] = __builtin_amdgcn_mfma_f32_16x16x32_bf16(bw, hf[mt], acc2[mt], 0, 0, 0);
                bw = bnx;
            }
        }
        __syncthreads();                  // B2: sH reads done; sO (alias) writable

        // ---- 5) sO staging -> block-linear full-line out writes ----
        float* sO = (float*)(sb + SH_OFF);
#pragma unroll
        for (int mt = 0; mt < 2; mt++) {
            int m = half * 32 + mt * 16 + l16;
            float* dst = sO + m * SO_LD + wn * 16 + quad * 4;
            dst[0] = acc2[mt][0] + b2v.x; dst[1] = acc2[mt][1] + b2v.y;
            dst[2] = acc2[mt][2] + b2v.z; dst[3] = acc2[mt][3] + b2v.w;
        }
        __syncthreads();                  // B3
#pragma unroll
        for (int it = 0; it < 2; it++) {
            int idx = tid + it * 1024;
            int row = idx >> 5, c4 = (idx & 31) * 4;
            int e = t * MT + row;
            if (e < E_TOTAL) {
                float4 v = *reinterpret_cast<const float4*>(sO + row * SO_LD + c4);
                *reinterpret_cast<float4*>(&out[(size_t)e * DOUT + c4]) = v;
            }
        }

        if (!hasN) break;

        // ---- 6) write-late staged gathers into nxt ----
        {
            char* seg2 = nxtA + 2 * SEG_B + grow * 256;
            *reinterpret_cast<short4*>(seg2 + ((l16 * 8) ^ grx)) = cvt4(efa);
            *reinterpret_cast<short4*>(seg2 + ((l16 * 8 + 128) ^ grx)) = cvt4(efb);
            if (!XB) {
#pragma unroll
                for (int s = 0; s < 2; s++) {
                    char* seg = nxtA + s * SEG_B + grow * 256;
                    *reinterpret_cast<short4*>(seg + ((l16 * 8) ^ grx)) = cvt4(xga[s]);
                    *reinterpret_cast<short4*>(seg + ((l16 * 8 + 128) ^ grx)) = cvt4(xgb[s]);
                }
            }
        }
        __syncthreads();                  // B4: nxt fully populated; sO reads done

        cur = nxt; t = tn;
    }
}

extern "C" void kernel_launch(void* const* d_in, const int* in_sizes, int n_in,
                              void* d_out, int out_size, void* d_ws, size_t ws_size,
                              hipStream_t stream) {
    const float* x  = (const float*)d_in[0];
    const int*   ei = (const int*)d_in[1];
    const float* ea = (const float*)d_in[2];
    const float* W1 = (const float*)d_in[3];
    const float* b1 = (const float*)d_in[4];
    const float* W2 = (const float*)d_in[5];
    const float* b2 = (const float*)d_in[6];
    float* outp = (float*)d_out;

    short* w1t = (short*)d_ws;                    // 384 KB
    short* w2t = w1t + DH * CIN;                  // 128 KB

    const size_t wt_bytes = (size_t)(DH * CIN + DOUT * DH) * 2;     // 512 KB
    const size_t xb_bytes = (size_t)N_NODES * DN * 2;               // 12.8 MB
    const bool has_xb = ws_size >= wt_bytes + xb_bytes;
    short* xbp = has_xb ? (w2t + DOUT * DH) : nullptr;

    prep_all<<<has_xb ? 3381 : 256, 256, 0, stream>>>(W1, W2, x, w1t, w2t, xbp);

    if (has_xb)
        edge_mlp<true><<<NPERS, 1024, 0, stream>>>(xbp, x, ei, ea, b1, b2, w1t, w2t, outp);
    else
        edge_mlp<false><<<NPERS, 1024, 0, stream>>>(nullptr, x, ei, ea, b1, b2, w1t, w2t, outp);
}